// Round 6
// baseline (892.851 us; speedup 1.0000x reference)
//
#include <hip/hip_runtime.h>

#define NN   100000   // nodes
#define EE   1600000  // edges
#define DD   64       // feature dim
#define DOUT 16       // output dim
#define CAP  64       // CSR slots per node (1 self + 63 edges; P(deg>63) ~ 1e-19)
#define BATCH 8       // nodes gathered per matmul phase (W-read amortization)

// --- binning pipeline params ---
#define EPB  8192                      // edges per block in hist/scatter
#define NBL  ((EE + EPB - 1) / EPB)    // 196 blocks
#define BSH  9                         // bucket = dst >> 9 (512 nodes/bucket)
#define NB   196                       // ceil(100000 / 512)

// ---------------------------------------------------------------------------
// K1: per-block histogram over NB dst-buckets; also zeroes cnt (replaces a
// hipMemsetAsync launch).
// ---------------------------------------------------------------------------
__global__ __launch_bounds__(256) void k_hist(const int* __restrict__ ei,
                                              int* __restrict__ hist,
                                              int* __restrict__ cnt) {
    for (int i = blockIdx.x * 256 + threadIdx.x; i < NN; i += NBL * 256)
        cnt[i] = 0;
    __shared__ int h[NB];
    for (int i = threadIdx.x; i < NB; i += 256) h[i] = 0;
    __syncthreads();
    int e0 = blockIdx.x * EPB;
    int e1 = min(e0 + EPB, EE);
    for (int e = e0 + (int)threadIdx.x; e < e1; e += 256) {
        int d = ei[EE + e];
        atomicAdd(&h[d >> BSH], 1);
    }
    __syncthreads();
    for (int i = threadIdx.x; i < NB; i += 256)
        hist[i * NBL + blockIdx.x] = h[i];
}

// ---------------------------------------------------------------------------
// K2: single-block exclusive scan of the NB*NBL histogram (in place); also
// zeroes the two sentinel rows (row NN of A and B).
// ---------------------------------------------------------------------------
__global__ __launch_bounds__(256) void k_scan(int* __restrict__ hist,
                                              float* __restrict__ As,
                                              float* __restrict__ Bs) {
    int t = threadIdx.x;
    if (t < DD) As[(size_t)NN * DD + t] = 0.f;
    else if (t < 2 * DD) Bs[(size_t)NN * DD + (t - DD)] = 0.f;

    const int TOT = NB * NBL;
    const int CH  = (TOT + 255) / 256;
    __shared__ int part[256];
    int lo = t * CH, hi = min(lo + CH, TOT);
    int s = 0;
    for (int i = lo; i < hi; ++i) s += hist[i];
    part[t] = s;
    __syncthreads();
    for (int off = 1; off < 256; off <<= 1) {   // Hillis-Steele inclusive
        int v = (t >= off) ? part[t - off] : 0;
        __syncthreads();
        part[t] += v;
        __syncthreads();
    }
    int base = (t == 0) ? 0 : part[t - 1];
    for (int i = lo; i < hi; ++i) {
        int v = hist[i];
        hist[i] = base;
        base += v;
    }
}

// ---------------------------------------------------------------------------
// K3: scatter edges into bucket-grouped int2(src,dst). Private (bucket,block)
// ranges -> sequential full-line 8B writes.
// ---------------------------------------------------------------------------
__global__ __launch_bounds__(256) void k_scatter(const int* __restrict__ ei,
                                                 const int* __restrict__ hist,
                                                 int2* __restrict__ bed) {
    __shared__ int cur[NB];
    for (int i = threadIdx.x; i < NB; i += 256)
        cur[i] = hist[i * NBL + blockIdx.x];
    __syncthreads();
    int e0 = blockIdx.x * EPB;
    int e1 = min(e0 + EPB, EE);
    for (int e = e0 + (int)threadIdx.x; e < e1; e += 256) {
        int s = ei[e], d = ei[EE + e];
        int p = atomicAdd(&cur[d >> BSH], 1);
        bed[p] = make_int2(s, d);
    }
}

// ---------------------------------------------------------------------------
// K4: build padded CSR bucket-by-bucket (128 KB window per bucket, L2-hot).
// ---------------------------------------------------------------------------
__global__ __launch_bounds__(256) void k_csr(const int2* __restrict__ bed,
                                             const int* __restrict__ hist,
                                             int* __restrict__ cnt,
                                             int* __restrict__ csr) {
    int b  = blockIdx.x;
    int lo = hist[b * NBL];
    int hi = (b == NB - 1) ? EE : hist[(b + 1) * NBL];
    for (int e = lo + (int)threadIdx.x; e < hi; e += 256) {
        int2 sd = bed[e];
        int pos = atomicAdd(&cnt[sd.y], 1);
        if (pos < CAP) csr[(size_t)sd.y * CAP + pos] = sd.x;
    }
}

// ---------------------------------------------------------------------------
// hp[n][j] = (sum_k in[n][k] * W[k][j]) * rsqrt(cnt[n]+1)  (layer-1 pre-xform)
// W in VGPRs; input rows read as wave-uniform float4 broadcasts (no LDS).
// ---------------------------------------------------------------------------
template <int ROWS>
__global__ __launch_bounds__(256) void k_gemm_scale(const float* __restrict__ in,
                                                    const float* __restrict__ W,
                                                    const int* __restrict__ cnt,
                                                    float* __restrict__ out) {
    const int lane = threadIdx.x & 63;
    const int wv   = threadIdx.x >> 6;
    float Wreg[DD];
#pragma unroll
    for (int k = 0; k < DD; ++k) Wreg[k] = W[k * DD + lane];  // coalesced

    int base = (blockIdx.x * 4 + wv) * ROWS;
    for (int r = 0; r < ROWS; ++r) {
        int n = base + r;
        if (n >= NN) return;
        const float4* row = (const float4*)(in + (size_t)n * DD);
        float acc = 0.f;
#pragma unroll
        for (int kk = 0; kk < DD / 4; ++kk) {
            float4 q = row[kk];  // uniform address -> broadcast
            acc = fmaf(q.x, Wreg[4 * kk + 0], acc);
            acc = fmaf(q.y, Wreg[4 * kk + 1], acc);
            acc = fmaf(q.z, Wreg[4 * kk + 2], acc);
            acc = fmaf(q.w, Wreg[4 * kk + 3], acc);
        }
        out[(size_t)n * DD + lane] = acc * rsqrtf((float)cnt[n] + 1.0f);
    }
}

// ---------------------------------------------------------------------------
// Gather one node's aggregated row (features 4m..4m+3, replicated in all
// lanes). Row indices come from 8 direct global b32 loads per lane (VMEM
// pipe, not LDS-pipe bpermutes). One branchless round of 8 dwordx4 covers
// deg<=31 (self + 31); rare wave-uniform 2nd round covers deg<=63.
// Sentinel: row NN is a zero row; OOB list slots load it (L1-hot).
// ---------------------------------------------------------------------------
__device__ __forceinline__ float4 gather_node(const float4* __restrict__ hpv,
                                              const int* __restrict__ crow,
                                              int n, int c, int sub, int m) {
    float4 fa = {0.f, 0.f, 0.f, 0.f}, fb = fa;
#define GROW(g, acc)                                                        \
    {                                                                       \
        int idx = 4 * (g) + sub;                                            \
        int rv  = crow[idx ? idx - 1 : 0];                                  \
        int row = (idx == 0) ? n : ((idx <= c) ? rv : NN);                  \
        float4 v = hpv[(size_t)row * 16 + m];                               \
        acc.x += v.x; acc.y += v.y; acc.z += v.z; acc.w += v.w;             \
    }
    GROW(0, fa) GROW(1, fb) GROW(2, fa) GROW(3, fb)
    GROW(4, fa) GROW(5, fb) GROW(6, fa) GROW(7, fb)
    if (c >= 32) {  // wave-uniform, P ~ 3e-4
#define GROW2(g, acc)                                                       \
        {                                                                   \
            int idx = 32 + 4 * (g) + sub;                                   \
            int rv  = crow[idx - 1];                                        \
            int row = (idx <= c) ? rv : NN;                                 \
            float4 v = hpv[(size_t)row * 16 + m];                           \
            acc.x += v.x; acc.y += v.y; acc.z += v.z; acc.w += v.w;         \
        }
        GROW2(0, fa) GROW2(1, fb) GROW2(2, fa) GROW2(3, fb)
        GROW2(4, fa) GROW2(5, fb) GROW2(6, fa) GROW2(7, fb)
#undef GROW2
    }
#undef GROW
    float4 s;
    s.x = fa.x + fb.x; s.y = fa.y + fb.y; s.z = fa.z + fb.z; s.w = fa.w + fb.w;
    s.x += __shfl_xor(s.x, 16); s.y += __shfl_xor(s.y, 16);
    s.z += __shfl_xor(s.z, 16); s.w += __shfl_xor(s.w, 16);
    s.x += __shfl_xor(s.x, 32); s.y += __shfl_xor(s.y, 32);
    s.z += __shfl_xor(s.z, 32); s.w += __shfl_xor(s.w, 32);
    return s;
}

// ---------------------------------------------------------------------------
// Fused layer: for batches of 8 nodes: gather+relu+bias -> t rows in LDS,
// then ONE matmul phase (W b32 reads amortized 8x; t as b128 broadcasts):
// hpn[n] = (t @ Wn) * rsqrt(cnt[n]+1). Grid-stride waves smooth the tail.
// ---------------------------------------------------------------------------
__global__ __launch_bounds__(256, 8) void k_fused(const float* __restrict__ hp,
                                                  const int* __restrict__ csr,
                                                  const int* __restrict__ cnt,
                                                  const float* __restrict__ bias,
                                                  const float* __restrict__ Wn,
                                                  float* __restrict__ hpn,
                                                  int nwaves) {
    __shared__ float sW[DD * DD];          // sW[k*64+j] = Wn[k][j]
    __shared__ float tbuf[4][BATCH][DD];   // per-wave t rows
    const int lane = threadIdx.x & 63;
    const int wv   = threadIdx.x >> 6;
    const int sub  = lane >> 4;
    const int m    = lane & 15;

    for (int i = threadIdx.x; i < DD * DD / 4; i += 256)
        ((float4*)sW)[i] = ((const float4*)Wn)[i];  // L2-broadcast staging
    __syncthreads();

    const float4 bv4 = ((const float4*)bias)[m];
    const float4* hpv = (const float4*)hp;
    const float*  wl  = sW + lane;
    const int wid = blockIdx.x * 4 + wv;

    for (int base = wid * BATCH; base < NN; base += nwaves * BATCH) {
        // ---- gather phase: 8 nodes -> tbuf ----
#pragma unroll
        for (int b = 0; b < BATCH; ++b) {
            int n  = base + b;
            int na = (n < NN) ? n : (NN - 1);   // clamp (waste, not hazard)
            int c  = cnt[na]; if (c > 63) c = 63;
            float4 s = gather_node(hpv, csr + (size_t)na * CAP, na, c, sub, m);
            float dv = rsqrtf((float)c + 1.0f);
            float4 t4;
            t4.x = fmaxf(fmaf(dv, s.x, bv4.x), 0.f);
            t4.y = fmaxf(fmaf(dv, s.y, bv4.y), 0.f);
            t4.z = fmaxf(fmaf(dv, s.z, bv4.z), 0.f);
            t4.w = fmaxf(fmaf(dv, s.w, bv4.w), 0.f);
            if (sub == 0) ((float4*)tbuf[wv][b])[m] = t4;
        }
        // ---- matmul phase: o[b][lane] = sum_k t[b][k] * W[k][lane] ----
        float o[BATCH];
#pragma unroll
        for (int b = 0; b < BATCH; ++b) o[b] = 0.f;
#pragma unroll
        for (int kk = 0; kk < DD / 4; ++kk) {
            float w0 = wl[(4 * kk + 0) * DD];
            float w1 = wl[(4 * kk + 1) * DD];
            float w2 = wl[(4 * kk + 2) * DD];
            float w3 = wl[(4 * kk + 3) * DD];
#pragma unroll
            for (int b = 0; b < BATCH; ++b) {
                float4 t4 = ((const float4*)tbuf[wv][b])[kk];  // broadcast
                o[b] = fmaf(t4.x, w0, fmaf(t4.y, w1,
                        fmaf(t4.z, w2, fmaf(t4.w, w3, o[b]))));
            }
        }
        // ---- store ----
#pragma unroll
        for (int b = 0; b < BATCH; ++b) {
            int n = base + b;
            if (n < NN)
                hpn[(size_t)n * DD + lane] =
                    o[b] * rsqrtf((float)cnt[n] + 1.0f);
        }
    }
}

// ---------------------------------------------------------------------------
// Final fused layer + FFN: t3 = relu(dinv*agg+b3); u = relu(t3@Wf1+bf1);
// out = u@Wf2 + bf2. Both matmuls batched over 8 nodes; tbuf reused for u.
// ---------------------------------------------------------------------------
__global__ __launch_bounds__(256, 8) void k_fused_ffn(const float* __restrict__ hp,
                                                      const int* __restrict__ csr,
                                                      const int* __restrict__ cnt,
                                                      const float* __restrict__ b3,
                                                      const float* __restrict__ Wf1,
                                                      const float* __restrict__ bf1,
                                                      const float* __restrict__ Wf2,
                                                      const float* __restrict__ bf2,
                                                      float* __restrict__ out,
                                                      int nwaves) {
    __shared__ float sW1[DD * DD];
    __shared__ float sW2[DD * DOUT];
    __shared__ float tbuf[4][BATCH][DD];   // t rows, then reused for u rows
    const int lane = threadIdx.x & 63;
    const int wv   = threadIdx.x >> 6;
    const int sub  = lane >> 4;
    const int m    = lane & 15;

    for (int i = threadIdx.x; i < DD * DD / 4; i += 256)
        ((float4*)sW1)[i] = ((const float4*)Wf1)[i];
    for (int i = threadIdx.x; i < DD * DOUT / 4; i += 256)
        ((float4*)sW2)[i] = ((const float4*)Wf2)[i];
    __syncthreads();

    const float4 b3v4 = ((const float4*)b3)[m];
    const float  b1v  = bf1[lane];
    const float  b2v  = bf2[m];
    const float4* hpv = (const float4*)hp;
    const float*  wl  = sW1 + lane;
    const float*  w2p = sW2 + (sub * 16) * DOUT + m;  // (sub*16+k')*16 + m
    const int wid = blockIdx.x * 4 + wv;

    for (int base = wid * BATCH; base < NN; base += nwaves * BATCH) {
        // ---- gather phase ----
#pragma unroll
        for (int b = 0; b < BATCH; ++b) {
            int n  = base + b;
            int na = (n < NN) ? n : (NN - 1);
            int c  = cnt[na]; if (c > 63) c = 63;
            float4 s = gather_node(hpv, csr + (size_t)na * CAP, na, c, sub, m);
            float dv = rsqrtf((float)c + 1.0f);
            float4 t4;
            t4.x = fmaxf(fmaf(dv, s.x, b3v4.x), 0.f);
            t4.y = fmaxf(fmaf(dv, s.y, b3v4.y), 0.f);
            t4.z = fmaxf(fmaf(dv, s.z, b3v4.z), 0.f);
            t4.w = fmaxf(fmaf(dv, s.w, b3v4.w), 0.f);
            if (sub == 0) ((float4*)tbuf[wv][b])[m] = t4;
        }
        // ---- u = relu(t @ Wf1 + bf1), batched ----
        float u[BATCH];
#pragma unroll
        for (int b = 0; b < BATCH; ++b) u[b] = b1v;
#pragma unroll
        for (int kk = 0; kk < DD / 4; ++kk) {
            float w0 = wl[(4 * kk + 0) * DD];
            float w1 = wl[(4 * kk + 1) * DD];
            float w2 = wl[(4 * kk + 2) * DD];
            float w3 = wl[(4 * kk + 3) * DD];
#pragma unroll
            for (int b = 0; b < BATCH; ++b) {
                float4 t4 = ((const float4*)tbuf[wv][b])[kk];
                u[b] = fmaf(t4.x, w0, fmaf(t4.y, w1,
                        fmaf(t4.z, w2, fmaf(t4.w, w3, u[b]))));
            }
        }
        // overwrite tbuf with u rows (wave-private; lgkmcnt orders RAW/WAR)
#pragma unroll
        for (int b = 0; b < BATCH; ++b)
            tbuf[wv][b][lane] = fmaxf(u[b], 0.f);
        // ---- out = u @ Wf2 + bf2 : quarter-K per sub, 2 xor-reduces ----
        float p[BATCH];
#pragma unroll
        for (int b = 0; b < BATCH; ++b) p[b] = 0.f;
#pragma unroll
        for (int kq = 0; kq < 4; ++kq) {
            float a0 = w2p[(4 * kq + 0) * DOUT];
            float a1 = w2p[(4 * kq + 1) * DOUT];
            float a2 = w2p[(4 * kq + 2) * DOUT];
            float a3 = w2p[(4 * kq + 3) * DOUT];
#pragma unroll
            for (int b = 0; b < BATCH; ++b) {
                float4 uq = ((const float4*)(tbuf[wv][b] + sub * 16))[kq];
                p[b] = fmaf(uq.x, a0, fmaf(uq.y, a1,
                        fmaf(uq.z, a2, fmaf(uq.w, a3, p[b]))));
            }
        }
#pragma unroll
        for (int b = 0; b < BATCH; ++b) {
            p[b] += __shfl_xor(p[b], 16);
            p[b] += __shfl_xor(p[b], 32);
            int n = base + b;
            if (lane < 16 && n < NN) out[(size_t)n * DOUT + m] = p[b] + b2v;
        }
    }
}

// ---------------------------------------------------------------------------
extern "C" void kernel_launch(void* const* d_in, const int* in_sizes, int n_in,
                              void* d_out, int out_size, void* d_ws, size_t ws_size,
                              hipStream_t stream) {
    const float* x   = (const float*)d_in[0];
    const int*   ei  = (const int*)d_in[1];
    const float* W1  = (const float*)d_in[2];
    const float* b1  = (const float*)d_in[3];
    const float* W2  = (const float*)d_in[4];
    const float* b2  = (const float*)d_in[5];
    const float* W3  = (const float*)d_in[6];
    const float* b3  = (const float*)d_in[7];
    const float* Wf1 = (const float*)d_in[8];
    const float* bf1 = (const float*)d_in[9];
    const float* Wf2 = (const float*)d_in[10];
    const float* bf2 = (const float*)d_in[11];
    float* out = (float*)d_out;

    char* ws = (char*)d_ws;
    auto al = [](size_t v) { return (v + 255) & ~(size_t)255; };
    size_t off = 0;
    int*   cnt  = (int*)(ws + off);   off = al(off + (size_t)NN * 4);
    int*   csr  = (int*)(ws + off);   off = al(off + (size_t)NN * CAP * 4);
    float* A    = (float*)(ws + off); off = al(off + (size_t)(NN + 1) * DD * 4);
    float* B    = (float*)(ws + off); off = al(off + (size_t)(NN + 1) * DD * 4);

    // Lifetime-disjoint aliases: binned int2 edges in A's first 12.8 MB
    // (overwritten later by k_gemm_scale); hist matrix in B's first 154 KB
    // (overwritten by fused layer-1 output). Sentinel rows at 25.6 MB are
    // beyond both aliases.
    int2* bed  = (int2*)A;
    int*  hist = (int*)B;

    k_hist<<<NBL, 256, 0, stream>>>(ei, hist, cnt);
    k_scan<<<1, 256, 0, stream>>>(hist, A, B);
    k_scatter<<<NBL, 256, 0, stream>>>(ei, hist, bed);
    k_csr<<<NB, 256, 0, stream>>>(bed, hist, cnt, csr);

    constexpr int ROWS = 16;
    int gg = (((NN + ROWS - 1) / ROWS) + 3) / 4;   // gemm grid (4 waves/block)
    // fused: LDS 24.6KB -> 6 blocks/CU; ffn: 28.7KB -> 5 blocks/CU.
    const int GF = 1536, GFF = 1280;
    const int WF = GF * 4, WFF = GFF * 4;          // grid-stride wave counts

    // layer 1 pre-transform: hp1 = (x@W1)*dinv   (overwrites binned edges)
    k_gemm_scale<ROWS><<<gg, 256, 0, stream>>>(x, W1, cnt, A);
    // fused layer 1->2: agg(hp1)+relu+b1, then hp2 = (t@W2)*dinv
    k_fused<<<GF, 256, 0, stream>>>(A, csr, cnt, b1, W2, B, WF);
    // fused layer 2->3
    k_fused<<<GF, 256, 0, stream>>>(B, csr, cnt, b2, W3, A, WF);
    // fused layer 3 + FFN -> out
    k_fused_ffn<<<GFF, 256, 0, stream>>>(A, csr, cnt, b3, Wf1, bf1, Wf2, bf2, out, WFF);
}

// Round 7
// 545.709 us; speedup vs baseline: 1.6361x; 1.6361x over previous
//
#include <hip/hip_runtime.h>

#define NN   100000   // nodes
#define EE   1600000  // edges
#define DD   64       // feature dim
#define DOUT 16       // output dim
#define CAP  64       // CSR slots per node (1 self + 63 edges; P(deg>63) ~ 1e-19)
#define NPW  8        // nodes per wave in fused kernels (serial, NOT batched!)
#define WPAD 68       // padded row stride (words) for transposed W in LDS

// --- binning pipeline params ---
#define EPB  8192                      // edges per block in hist/scatter
#define NBL  ((EE + EPB - 1) / EPB)    // 196 blocks
#define BSH  9                         // bucket = dst >> 9 (512 nodes/bucket)
#define NB   196                       // ceil(100000 / 512)

// ---------------------------------------------------------------------------
// K1: per-block histogram over NB dst-buckets; also zeroes cnt.
// ---------------------------------------------------------------------------
__global__ __launch_bounds__(256) void k_hist(const int* __restrict__ ei,
                                              int* __restrict__ hist,
                                              int* __restrict__ cnt) {
    for (int i = blockIdx.x * 256 + threadIdx.x; i < NN; i += NBL * 256)
        cnt[i] = 0;
    __shared__ int h[NB];
    for (int i = threadIdx.x; i < NB; i += 256) h[i] = 0;
    __syncthreads();
    int e0 = blockIdx.x * EPB;
    int e1 = min(e0 + EPB, EE);
    for (int e = e0 + (int)threadIdx.x; e < e1; e += 256) {
        int d = ei[EE + e];
        atomicAdd(&h[d >> BSH], 1);
    }
    __syncthreads();
    for (int i = threadIdx.x; i < NB; i += 256)
        hist[i * NBL + blockIdx.x] = h[i];
}

// ---------------------------------------------------------------------------
// K2: single-block exclusive scan of the NB*NBL histogram (in place); also
// zeroes the two sentinel rows (row NN of A and B).
// ---------------------------------------------------------------------------
__global__ __launch_bounds__(256) void k_scan(int* __restrict__ hist,
                                              float* __restrict__ As,
                                              float* __restrict__ Bs) {
    int t = threadIdx.x;
    if (t < DD) As[(size_t)NN * DD + t] = 0.f;
    else if (t < 2 * DD) Bs[(size_t)NN * DD + (t - DD)] = 0.f;

    const int TOT = NB * NBL;
    const int CH  = (TOT + 255) / 256;
    __shared__ int part[256];
    int lo = t * CH, hi = min(lo + CH, TOT);
    int s = 0;
    for (int i = lo; i < hi; ++i) s += hist[i];
    part[t] = s;
    __syncthreads();
    for (int off = 1; off < 256; off <<= 1) {   // Hillis-Steele inclusive
        int v = (t >= off) ? part[t - off] : 0;
        __syncthreads();
        part[t] += v;
        __syncthreads();
    }
    int base = (t == 0) ? 0 : part[t - 1];
    for (int i = lo; i < hi; ++i) {
        int v = hist[i];
        hist[i] = base;
        base += v;
    }
}

// ---------------------------------------------------------------------------
// K3: scatter edges into bucket-grouped int2(src,dst). Private (bucket,block)
// ranges -> sequential full-line 8B writes.
// ---------------------------------------------------------------------------
__global__ __launch_bounds__(256) void k_scatter(const int* __restrict__ ei,
                                                 const int* __restrict__ hist,
                                                 int2* __restrict__ bed) {
    __shared__ int cur[NB];
    for (int i = threadIdx.x; i < NB; i += 256)
        cur[i] = hist[i * NBL + blockIdx.x];
    __syncthreads();
    int e0 = blockIdx.x * EPB;
    int e1 = min(e0 + EPB, EE);
    for (int e = e0 + (int)threadIdx.x; e < e1; e += 256) {
        int s = ei[e], d = ei[EE + e];
        int p = atomicAdd(&cur[d >> BSH], 1);
        bed[p] = make_int2(s, d);
    }
}

// ---------------------------------------------------------------------------
// K4: build padded CSR bucket-by-bucket (128 KB window per bucket, L2-hot).
// ---------------------------------------------------------------------------
__global__ __launch_bounds__(256) void k_csr(const int2* __restrict__ bed,
                                             const int* __restrict__ hist,
                                             int* __restrict__ cnt,
                                             int* __restrict__ csr) {
    int b  = blockIdx.x;
    int lo = hist[b * NBL];
    int hi = (b == NB - 1) ? EE : hist[(b + 1) * NBL];
    for (int e = lo + (int)threadIdx.x; e < hi; e += 256) {
        int2 sd = bed[e];
        int pos = atomicAdd(&cnt[sd.y], 1);
        if (pos < CAP) csr[(size_t)sd.y * CAP + pos] = sd.x;
    }
}

// ---------------------------------------------------------------------------
// hp[n][j] = (sum_k in[n][k] * W[k][j]) * rsqrt(cnt[n]+1)  (layer-1 pre-xform)
// W in VGPRs; input rows read as wave-uniform float4 broadcasts.
// ---------------------------------------------------------------------------
template <int ROWS>
__global__ __launch_bounds__(256) void k_gemm_scale(const float* __restrict__ in,
                                                    const float* __restrict__ W,
                                                    const int* __restrict__ cnt,
                                                    float* __restrict__ out) {
    const int lane = threadIdx.x & 63;
    const int wv   = threadIdx.x >> 6;
    float Wreg[DD];
#pragma unroll
    for (int k = 0; k < DD; ++k) Wreg[k] = W[k * DD + lane];  // coalesced

    int base = (blockIdx.x * 4 + wv) * ROWS;
    for (int r = 0; r < ROWS; ++r) {
        int n = base + r;
        if (n >= NN) return;
        const float4* row = (const float4*)(in + (size_t)n * DD);
        float acc = 0.f;
#pragma unroll
        for (int kk = 0; kk < DD / 4; ++kk) {
            float4 q = row[kk];  // uniform address -> broadcast
            acc = fmaf(q.x, Wreg[4 * kk + 0], acc);
            acc = fmaf(q.y, Wreg[4 * kk + 1], acc);
            acc = fmaf(q.z, Wreg[4 * kk + 2], acc);
            acc = fmaf(q.w, Wreg[4 * kk + 3], acc);
        }
        out[(size_t)n * DD + lane] = acc * rsqrtf((float)cnt[n] + 1.0f);
    }
}

// ---------------------------------------------------------------------------
// Gather one node's aggregated row (features 4m..4m+3, replicated in all
// lanes after the xor-reduce). Row indices: direct global b32 loads (VMEM
// pipe, no bpermute). One branchless round of 8 dwordx4 covers deg<=31;
// rare wave-uniform 2nd round covers deg<=63. Row NN is a zero sentinel.
// Only 2 float4 accumulators -> no register blow-up (DO NOT batch nodes:
// round-6 showed 8 interleaved gathers -> 256 VGPR -> scratch spills).
// ---------------------------------------------------------------------------
__device__ __forceinline__ float4 gather_node(const float4* __restrict__ hpv,
                                              const int* __restrict__ crow,
                                              int n, int c, int sub, int m) {
    float4 fa = {0.f, 0.f, 0.f, 0.f}, fb = fa;
#define GROW(g, acc)                                                        \
    {                                                                       \
        int idx = 4 * (g) + sub;                                            \
        int rv  = crow[idx ? idx - 1 : 0];                                  \
        int row = (idx == 0) ? n : ((idx <= c) ? rv : NN);                  \
        float4 v = hpv[(size_t)row * 16 + m];                               \
        acc.x += v.x; acc.y += v.y; acc.z += v.z; acc.w += v.w;             \
    }
    GROW(0, fa) GROW(1, fb) GROW(2, fa) GROW(3, fb)
    GROW(4, fa) GROW(5, fb) GROW(6, fa) GROW(7, fb)
    if (c >= 32) {  // wave-uniform, P ~ 3e-4
#define GROW2(g, acc)                                                       \
        {                                                                   \
            int idx = 32 + 4 * (g) + sub;                                   \
            int rv  = crow[idx - 1];                                        \
            int row = (idx <= c) ? rv : NN;                                 \
            float4 v = hpv[(size_t)row * 16 + m];                           \
            acc.x += v.x; acc.y += v.y; acc.z += v.z; acc.w += v.w;         \
        }
        GROW2(0, fa) GROW2(1, fb) GROW2(2, fa) GROW2(3, fb)
        GROW2(4, fa) GROW2(5, fb) GROW2(6, fa) GROW2(7, fb)
#undef GROW2
    }
#undef GROW
    float4 s;
    s.x = fa.x + fb.x; s.y = fa.y + fb.y; s.z = fa.z + fb.z; s.w = fa.w + fb.w;
    s.x += __shfl_xor(s.x, 16); s.y += __shfl_xor(s.y, 16);
    s.z += __shfl_xor(s.z, 16); s.w += __shfl_xor(s.w, 16);
    s.x += __shfl_xor(s.x, 32); s.y += __shfl_xor(s.y, 32);
    s.z += __shfl_xor(s.z, 32); s.w += __shfl_xor(s.w, 32);
    return s;
}

// ---------------------------------------------------------------------------
// Stage W transposed+padded into LDS: sWt[j*WPAD + k] = W[k*64 + j].
// Lane stride 68 words = 272 B (16B-aligned); a 64-lane b128 read of column
// j hits banks (4j+4k)%32 -> meets the 8-clk LDS floor, conflict-free.
// ---------------------------------------------------------------------------
__device__ __forceinline__ void stage_wt(const float* __restrict__ W,
                                         float* __restrict__ sWt, int tid) {
    for (int i = tid; i < DD * DD; i += 256) {
        int k = i >> 6, j = i & 63;
        sWt[j * WPAD + k] = W[i];   // coalesced global read, once per block
    }
}

// ---------------------------------------------------------------------------
// Fused layer: t = relu(dinv[n]*agg + bias); hpn[n] = (t @ Wn) * dinv[n].
// Per-node serial loop. Matmul: 16 ds_read_b128 of W-column (was 64 b32) +
// 16 wave-uniform b128 broadcasts of t.
// ---------------------------------------------------------------------------
__global__ __launch_bounds__(256, 8) void k_fused(const float* __restrict__ hp,
                                                  const int* __restrict__ csr,
                                                  const int* __restrict__ cnt,
                                                  const float* __restrict__ bias,
                                                  const float* __restrict__ Wn,
                                                  float* __restrict__ hpn) {
    __shared__ float sWt[DD * WPAD];
    __shared__ float tbuf[4][DD];
    const int lane = threadIdx.x & 63;
    const int wv   = threadIdx.x >> 6;
    const int sub  = lane >> 4;
    const int m    = lane & 15;

    stage_wt(Wn, sWt, threadIdx.x);
    __syncthreads();

    const float4  bv4 = ((const float4*)bias)[m];
    const float4* hpv = (const float4*)hp;
    const float4* wcol = (const float4*)(sWt + lane * WPAD);

    int base = (blockIdx.x * 4 + wv) * NPW;
    for (int r = 0; r < NPW; ++r) {
        int n = base + r;
        if (n >= NN) return;
        int c = cnt[n]; if (c > 63) c = 63;
        float dv = rsqrtf((float)cnt[n] + 1.0f);
        float4 s = gather_node(hpv, csr + (size_t)n * CAP, n, c, sub, m);
        float4 t4;
        t4.x = fmaxf(fmaf(dv, s.x, bv4.x), 0.f);
        t4.y = fmaxf(fmaf(dv, s.y, bv4.y), 0.f);
        t4.z = fmaxf(fmaf(dv, s.z, bv4.z), 0.f);
        t4.w = fmaxf(fmaf(dv, s.w, bv4.w), 0.f);

        if (sub == 0) ((float4*)tbuf[wv])[m] = t4;  // wave-private slot
        const float4* tb = (const float4*)tbuf[wv];
        float o = 0.f;
#pragma unroll
        for (int kk = 0; kk < DD / 4; ++kk) {
            float4 w = wcol[kk];   // b128, conflict-free via WPAD
            float4 q = tb[kk];     // wave-uniform -> broadcast
            o = fmaf(q.x, w.x, fmaf(q.y, w.y, fmaf(q.z, w.z, fmaf(q.w, w.w, o))));
        }
        hpn[(size_t)n * DD + lane] = o * dv;
    }
}

// ---------------------------------------------------------------------------
// Final fused layer + FFN: t3 = relu(dinv*agg+b3); u = relu(t3@Wf1+bf1);
// out = u@Wf2 + bf2.  Wf1 transposed+padded in LDS; Wf2 (4 KB) b32 reads.
// ---------------------------------------------------------------------------
__global__ __launch_bounds__(256, 8) void k_fused_ffn(const float* __restrict__ hp,
                                                      const int* __restrict__ csr,
                                                      const int* __restrict__ cnt,
                                                      const float* __restrict__ b3,
                                                      const float* __restrict__ Wf1,
                                                      const float* __restrict__ bf1,
                                                      const float* __restrict__ Wf2,
                                                      const float* __restrict__ bf2,
                                                      float* __restrict__ out) {
    __shared__ float sW1t[DD * WPAD];
    __shared__ float sW2[DD * DOUT];
    __shared__ float tbuf[4][DD];
    __shared__ float ubuf[4][DD];
    const int lane = threadIdx.x & 63;
    const int wv   = threadIdx.x >> 6;
    const int sub  = lane >> 4;   // also the K-quarter for the 2nd matmul
    const int m    = lane & 15;

    stage_wt(Wf1, sW1t, threadIdx.x);
    for (int i = threadIdx.x; i < DD * DOUT / 4; i += 256)
        ((float4*)sW2)[i] = ((const float4*)Wf2)[i];
    __syncthreads();

    const float4 b3v4 = ((const float4*)b3)[m];
    const float  b1v  = bf1[lane];
    const float  b2v  = bf2[m];
    const float4* hpv  = (const float4*)hp;
    const float4* w1col = (const float4*)(sW1t + lane * WPAD);
    const float*  w2p   = sW2 + (sub * 16) * DOUT + m;  // (sub*16+k')*16 + m

    int base = (blockIdx.x * 4 + wv) * NPW;
    for (int r = 0; r < NPW; ++r) {
        int n = base + r;
        if (n >= NN) return;
        int c = cnt[n]; if (c > 63) c = 63;
        float dv = rsqrtf((float)cnt[n] + 1.0f);
        float4 s = gather_node(hpv, csr + (size_t)n * CAP, n, c, sub, m);
        float4 t4;
        t4.x = fmaxf(fmaf(dv, s.x, b3v4.x), 0.f);
        t4.y = fmaxf(fmaf(dv, s.y, b3v4.y), 0.f);
        t4.z = fmaxf(fmaf(dv, s.z, b3v4.z), 0.f);
        t4.w = fmaxf(fmaf(dv, s.w, b3v4.w), 0.f);

        if (sub == 0) ((float4*)tbuf[wv])[m] = t4;
        const float4* tb = (const float4*)tbuf[wv];
        float u = b1v;
#pragma unroll
        for (int kk = 0; kk < DD / 4; ++kk) {
            float4 w = w1col[kk];
            float4 q = tb[kk];
            u = fmaf(q.x, w.x, fmaf(q.y, w.y, fmaf(q.z, w.z, fmaf(q.w, w.w, u))));
        }
        u = fmaxf(u, 0.f);

        // out = u @ Wf2 + bf2 : lane (sub,m) does quarter-K partial, 2 xor-reduces
        ubuf[wv][lane] = u;
        const float4* ub = (const float4*)(ubuf[wv] + sub * 16);
        float p = 0.f;
#pragma unroll
        for (int kq = 0; kq < 4; ++kq) {
            float4 z = ub[kq];
            p = fmaf(z.x, w2p[(4 * kq + 0) * DOUT],
                fmaf(z.y, w2p[(4 * kq + 1) * DOUT],
                fmaf(z.z, w2p[(4 * kq + 2) * DOUT],
                fmaf(z.w, w2p[(4 * kq + 3) * DOUT], p))));
        }
        p += __shfl_xor(p, 16);
        p += __shfl_xor(p, 32);
        if (lane < 16) out[(size_t)n * DOUT + m] = p + b2v;
    }
}

// ---------------------------------------------------------------------------
extern "C" void kernel_launch(void* const* d_in, const int* in_sizes, int n_in,
                              void* d_out, int out_size, void* d_ws, size_t ws_size,
                              hipStream_t stream) {
    const float* x   = (const float*)d_in[0];
    const int*   ei  = (const int*)d_in[1];
    const float* W1  = (const float*)d_in[2];
    const float* b1  = (const float*)d_in[3];
    const float* W2  = (const float*)d_in[4];
    const float* b2  = (const float*)d_in[5];
    const float* W3  = (const float*)d_in[6];
    const float* b3  = (const float*)d_in[7];
    const float* Wf1 = (const float*)d_in[8];
    const float* bf1 = (const float*)d_in[9];
    const float* Wf2 = (const float*)d_in[10];
    const float* bf2 = (const float*)d_in[11];
    float* out = (float*)d_out;

    char* ws = (char*)d_ws;
    auto al = [](size_t v) { return (v + 255) & ~(size_t)255; };
    size_t off = 0;
    int*   cnt  = (int*)(ws + off);   off = al(off + (size_t)NN * 4);
    int*   csr  = (int*)(ws + off);   off = al(off + (size_t)NN * CAP * 4);
    float* A    = (float*)(ws + off); off = al(off + (size_t)(NN + 1) * DD * 4);
    float* B    = (float*)(ws + off); off = al(off + (size_t)(NN + 1) * DD * 4);

    // Lifetime-disjoint aliases: binned int2 edges in A's first 12.8 MB
    // (overwritten later by k_gemm_scale); hist matrix in B's first 154 KB
    // (overwritten by fused layer-1 output). Sentinel rows are beyond both.
    int2* bed  = (int2*)A;
    int*  hist = (int*)B;

    k_hist<<<NBL, 256, 0, stream>>>(ei, hist, cnt);
    k_scan<<<1, 256, 0, stream>>>(hist, A, B);
    k_scatter<<<NBL, 256, 0, stream>>>(ei, hist, bed);
    k_csr<<<NB, 256, 0, stream>>>(bed, hist, cnt, csr);

    constexpr int ROWS = 16;
    int gg = (((NN + ROWS - 1) / ROWS) + 3) / 4;   // gemm grid (4 waves/block)
    int gf = (NN + 4 * NPW - 1) / (4 * NPW);       // fused grid: 3125 blocks (exact)

    // layer 1 pre-transform: hp1 = (x@W1)*dinv   (overwrites binned edges)
    k_gemm_scale<ROWS><<<gg, 256, 0, stream>>>(x, W1, cnt, A);
    // fused layer 1->2: agg(hp1)+relu+b1, then hp2 = (t@W2)*dinv
    k_fused<<<gf, 256, 0, stream>>>(A, csr, cnt, b1, W2, B);
    // fused layer 2->3
    k_fused<<<gf, 256, 0, stream>>>(B, csr, cnt, b2, W3, A);
    // fused layer 3 + FFN -> out
    k_fused_ffn<<<gf, 256, 0, stream>>>(A, csr, cnt, b3, Wf1, bf1, Wf2, bf2, out);
}

// Round 8
// 474.111 us; speedup vs baseline: 1.8832x; 1.1510x over previous
//
#include <hip/hip_runtime.h>

#define NN   100000   // nodes
#define EE   1600000  // edges
#define DD   64       // feature dim
#define DOUT 16       // output dim
#define CAP  64       // CSR slots per node (1 self + 63 edges; P(deg>63) ~ 1e-19)
#define NPW  8        // nodes per wave in fused kernels (serial, NOT batched!)
#define WPAD 68       // padded row stride (words) for transposed W in LDS

// --- binning pipeline params ---
#define EPB  8192                      // edges per block in hist/scatter
#define NBL  ((EE + EPB - 1) / EPB)    // 196 blocks
#define BSH  9                         // bucket = dst >> 9 (512 nodes/bucket)
#define NB   196                       // ceil(100000 / 512)

// ---------------------------------------------------------------------------
// K1: per-block histogram over NB dst-buckets; also zeroes cnt.
// ---------------------------------------------------------------------------
__global__ __launch_bounds__(256) void k_hist(const int* __restrict__ ei,
                                              int* __restrict__ hist,
                                              int* __restrict__ cnt) {
    for (int i = blockIdx.x * 256 + threadIdx.x; i < NN; i += NBL * 256)
        cnt[i] = 0;
    __shared__ int h[NB];
    for (int i = threadIdx.x; i < NB; i += 256) h[i] = 0;
    __syncthreads();
    int e0 = blockIdx.x * EPB;
    int e1 = min(e0 + EPB, EE);
    for (int e = e0 + (int)threadIdx.x; e < e1; e += 256) {
        int d = ei[EE + e];
        atomicAdd(&h[d >> BSH], 1);
    }
    __syncthreads();
    for (int i = threadIdx.x; i < NB; i += 256)
        hist[i * NBL + blockIdx.x] = h[i];
}

// ---------------------------------------------------------------------------
// K2: single-block exclusive scan of the NB*NBL histogram (in place); also
// zeroes the two sentinel rows (row NN of A and B).
// ---------------------------------------------------------------------------
__global__ __launch_bounds__(256) void k_scan(int* __restrict__ hist,
                                              float* __restrict__ As,
                                              float* __restrict__ Bs) {
    int t = threadIdx.x;
    if (t < DD) As[(size_t)NN * DD + t] = 0.f;
    else if (t < 2 * DD) Bs[(size_t)NN * DD + (t - DD)] = 0.f;

    const int TOT = NB * NBL;
    const int CH  = (TOT + 255) / 256;
    __shared__ int part[256];
    int lo = t * CH, hi = min(lo + CH, TOT);
    int s = 0;
    for (int i = lo; i < hi; ++i) s += hist[i];
    part[t] = s;
    __syncthreads();
    for (int off = 1; off < 256; off <<= 1) {   // Hillis-Steele inclusive
        int v = (t >= off) ? part[t - off] : 0;
        __syncthreads();
        part[t] += v;
        __syncthreads();
    }
    int base = (t == 0) ? 0 : part[t - 1];
    for (int i = lo; i < hi; ++i) {
        int v = hist[i];
        hist[i] = base;
        base += v;
    }
}

// ---------------------------------------------------------------------------
// K3: scatter edges into bucket-grouped int2(src,dst). Private (bucket,block)
// ranges -> sequential full-line 8B writes.
// ---------------------------------------------------------------------------
__global__ __launch_bounds__(256) void k_scatter(const int* __restrict__ ei,
                                                 const int* __restrict__ hist,
                                                 int2* __restrict__ bed) {
    __shared__ int cur[NB];
    for (int i = threadIdx.x; i < NB; i += 256)
        cur[i] = hist[i * NBL + blockIdx.x];
    __syncthreads();
    int e0 = blockIdx.x * EPB;
    int e1 = min(e0 + EPB, EE);
    for (int e = e0 + (int)threadIdx.x; e < e1; e += 256) {
        int s = ei[e], d = ei[EE + e];
        int p = atomicAdd(&cur[d >> BSH], 1);
        bed[p] = make_int2(s, d);
    }
}

// ---------------------------------------------------------------------------
// K4: build padded CSR bucket-by-bucket (128 KB window per bucket, L2-hot).
// ---------------------------------------------------------------------------
__global__ __launch_bounds__(256) void k_csr(const int2* __restrict__ bed,
                                             const int* __restrict__ hist,
                                             int* __restrict__ cnt,
                                             int* __restrict__ csr) {
    int b  = blockIdx.x;
    int lo = hist[b * NBL];
    int hi = (b == NB - 1) ? EE : hist[(b + 1) * NBL];
    for (int e = lo + (int)threadIdx.x; e < hi; e += 256) {
        int2 sd = bed[e];
        int pos = atomicAdd(&cnt[sd.y], 1);
        if (pos < CAP) csr[(size_t)sd.y * CAP + pos] = sd.x;
    }
}

// ---------------------------------------------------------------------------
// K5: xs[n] = x[n] * rsqrt(cnt[n]+1). Pure streaming, per-lane coalesced
// float4 (NO wave-uniform global loads, NO register arrays — the round-7
// k_gemm_scale was 110us because the compiler rematerialized its W array
// as per-row L1 re-loads; this kernel replaces it via gather linearity:
// agg(x@W1 * dinv) == agg(x*dinv) @ W1).
// ---------------------------------------------------------------------------
__global__ __launch_bounds__(256) void k_scale(const float* __restrict__ x,
                                               const int* __restrict__ cnt,
                                               float* __restrict__ xs) {
    int idx = blockIdx.x * 256 + threadIdx.x;   // one float4 per thread
    if (idx >= NN * (DD / 4)) return;
    int n = idx >> 4;
    float dv = rsqrtf((float)cnt[n] + 1.0f);
    float4 v = ((const float4*)x)[idx];
    v.x *= dv; v.y *= dv; v.z *= dv; v.w *= dv;
    ((float4*)xs)[idx] = v;
}

// ---------------------------------------------------------------------------
// Gather one node's aggregated row (features 4m..4m+3, replicated in all
// lanes after the xor-reduce). Row indices: direct global b32 loads (VMEM
// pipe). One branchless round of 8 dwordx4 covers deg<=31; rare wave-uniform
// 2nd round covers deg<=63. Row NN is a zero sentinel. Only 2 float4
// accumulators (round-6: batching gathers -> 256 VGPR -> scratch spills).
// ---------------------------------------------------------------------------
__device__ __forceinline__ float4 gather_node(const float4* __restrict__ hpv,
                                              const int* __restrict__ crow,
                                              int n, int c, int sub, int m) {
    float4 fa = {0.f, 0.f, 0.f, 0.f}, fb = fa;
#define GROW(g, acc)                                                        \
    {                                                                       \
        int idx = 4 * (g) + sub;                                            \
        int rv  = crow[idx ? idx - 1 : 0];                                  \
        int row = (idx == 0) ? n : ((idx <= c) ? rv : NN);                  \
        float4 v = hpv[(size_t)row * 16 + m];                               \
        acc.x += v.x; acc.y += v.y; acc.z += v.z; acc.w += v.w;             \
    }
    GROW(0, fa) GROW(1, fb) GROW(2, fa) GROW(3, fb)
    GROW(4, fa) GROW(5, fb) GROW(6, fa) GROW(7, fb)
    if (c >= 32) {  // wave-uniform, P ~ 3e-4
#define GROW2(g, acc)                                                       \
        {                                                                   \
            int idx = 32 + 4 * (g) + sub;                                   \
            int rv  = crow[idx - 1];                                        \
            int row = (idx <= c) ? rv : NN;                                 \
            float4 v = hpv[(size_t)row * 16 + m];                           \
            acc.x += v.x; acc.y += v.y; acc.z += v.z; acc.w += v.w;         \
        }
        GROW2(0, fa) GROW2(1, fb) GROW2(2, fa) GROW2(3, fb)
        GROW2(4, fa) GROW2(5, fb) GROW2(6, fa) GROW2(7, fb)
#undef GROW2
    }
#undef GROW
    float4 s;
    s.x = fa.x + fb.x; s.y = fa.y + fb.y; s.z = fa.z + fb.z; s.w = fa.w + fb.w;
    s.x += __shfl_xor(s.x, 16); s.y += __shfl_xor(s.y, 16);
    s.z += __shfl_xor(s.z, 16); s.w += __shfl_xor(s.w, 16);
    s.x += __shfl_xor(s.x, 32); s.y += __shfl_xor(s.y, 32);
    s.z += __shfl_xor(s.z, 32); s.w += __shfl_xor(s.w, 32);
    return s;
}

// ---------------------------------------------------------------------------
// Stage W transposed+padded into LDS: sWt[j*WPAD + k] = W[k*64 + j].
// Lane stride 68 words; per 16-lane phase of a b128 read banks repeat 2-way
// (free per m136).
// ---------------------------------------------------------------------------
__device__ __forceinline__ void stage_wt(const float* __restrict__ W,
                                         float* __restrict__ sWt, int tid) {
    for (int i = tid; i < DD * DD; i += 256) {
        int k = i >> 6, j = i & 63;
        sWt[j * WPAD + k] = W[i];   // coalesced global read, once per block
    }
}

// ---------------------------------------------------------------------------
// Fused layer 1: aggx = gather(xs); t1 = relu(dinv*(aggx@W1) + b1);
//                hp1[n] = (t1 @ W2) * dinv.   Two chained b128-LDS matmuls.
// ---------------------------------------------------------------------------
__global__ __launch_bounds__(256, 4) void k_fused_l1(const float* __restrict__ xs,
                                                     const int* __restrict__ csr,
                                                     const int* __restrict__ cnt,
                                                     const float* __restrict__ b1,
                                                     const float* __restrict__ W1,
                                                     const float* __restrict__ W2,
                                                     float* __restrict__ hpn) {
    __shared__ float sW1t[DD * WPAD];
    __shared__ float sW2t[DD * WPAD];
    __shared__ float abuf[4][DD];
    __shared__ float tbuf[4][DD];
    const int lane = threadIdx.x & 63;
    const int wv   = threadIdx.x >> 6;
    const int sub  = lane >> 4;
    const int m    = lane & 15;

    stage_wt(W1, sW1t, threadIdx.x);
    stage_wt(W2, sW2t, threadIdx.x);
    __syncthreads();

    const float  b1v = b1[lane];
    const float4* hpv  = (const float4*)xs;
    const float4* w1col = (const float4*)(sW1t + lane * WPAD);
    const float4* w2col = (const float4*)(sW2t + lane * WPAD);

    int base = (blockIdx.x * 4 + wv) * NPW;
    for (int r = 0; r < NPW; ++r) {
        int n = base + r;
        if (n >= NN) return;
        int c = cnt[n]; if (c > 63) c = 63;
        float dv = rsqrtf((float)c + 1.0f);
        float4 s = gather_node(hpv, csr + (size_t)n * CAP, n, c, sub, m);
        if (sub == 0) ((float4*)abuf[wv])[m] = s;   // aggx row -> LDS

        const float4* ab = (const float4*)abuf[wv];
        float v = 0.f;
#pragma unroll
        for (int kk = 0; kk < DD / 4; ++kk) {
            float4 w = w1col[kk];   // b128, 2-way-free banks via WPAD
            float4 q = ab[kk];      // wave-uniform -> LDS broadcast
            v = fmaf(q.x, w.x, fmaf(q.y, w.y, fmaf(q.z, w.z, fmaf(q.w, w.w, v))));
        }
        float t1 = fmaxf(fmaf(dv, v, b1v), 0.f);

        tbuf[wv][lane] = t1;
        const float4* tb = (const float4*)tbuf[wv];
        float o = 0.f;
#pragma unroll
        for (int kk = 0; kk < DD / 4; ++kk) {
            float4 w = w2col[kk];
            float4 q = tb[kk];
            o = fmaf(q.x, w.x, fmaf(q.y, w.y, fmaf(q.z, w.z, fmaf(q.w, w.w, o))));
        }
        hpn[(size_t)n * DD + lane] = o * dv;
    }
}

// ---------------------------------------------------------------------------
// Fused layer: t = relu(dinv[n]*agg + bias); hpn[n] = (t @ Wn) * dinv[n].
// ---------------------------------------------------------------------------
__global__ __launch_bounds__(256, 8) void k_fused(const float* __restrict__ hp,
                                                  const int* __restrict__ csr,
                                                  const int* __restrict__ cnt,
                                                  const float* __restrict__ bias,
                                                  const float* __restrict__ Wn,
                                                  float* __restrict__ hpn) {
    __shared__ float sWt[DD * WPAD];
    __shared__ float tbuf[4][DD];
    const int lane = threadIdx.x & 63;
    const int wv   = threadIdx.x >> 6;
    const int sub  = lane >> 4;
    const int m    = lane & 15;

    stage_wt(Wn, sWt, threadIdx.x);
    __syncthreads();

    const float4  bv4 = ((const float4*)bias)[m];
    const float4* hpv = (const float4*)hp;
    const float4* wcol = (const float4*)(sWt + lane * WPAD);

    int base = (blockIdx.x * 4 + wv) * NPW;
    for (int r = 0; r < NPW; ++r) {
        int n = base + r;
        if (n >= NN) return;
        int c = cnt[n]; if (c > 63) c = 63;
        float dv = rsqrtf((float)cnt[n] + 1.0f);
        float4 s = gather_node(hpv, csr + (size_t)n * CAP, n, c, sub, m);
        float4 t4;
        t4.x = fmaxf(fmaf(dv, s.x, bv4.x), 0.f);
        t4.y = fmaxf(fmaf(dv, s.y, bv4.y), 0.f);
        t4.z = fmaxf(fmaf(dv, s.z, bv4.z), 0.f);
        t4.w = fmaxf(fmaf(dv, s.w, bv4.w), 0.f);

        if (sub == 0) ((float4*)tbuf[wv])[m] = t4;  // wave-private slot
        const float4* tb = (const float4*)tbuf[wv];
        float o = 0.f;
#pragma unroll
        for (int kk = 0; kk < DD / 4; ++kk) {
            float4 w = wcol[kk];
            float4 q = tb[kk];
            o = fmaf(q.x, w.x, fmaf(q.y, w.y, fmaf(q.z, w.z, fmaf(q.w, w.w, o))));
        }
        hpn[(size_t)n * DD + lane] = o * dv;
    }
}

// ---------------------------------------------------------------------------
// Final fused layer + FFN: t3 = relu(dinv*agg+b3); u = relu(t3@Wf1+bf1);
// out = u@Wf2 + bf2.  Wf1 transposed+padded in LDS; Wf2 (4 KB) b32 reads.
// ---------------------------------------------------------------------------
__global__ __launch_bounds__(256, 8) void k_fused_ffn(const float* __restrict__ hp,
                                                      const int* __restrict__ csr,
                                                      const int* __restrict__ cnt,
                                                      const float* __restrict__ b3,
                                                      const float* __restrict__ Wf1,
                                                      const float* __restrict__ bf1,
                                                      const float* __restrict__ Wf2,
                                                      const float* __restrict__ bf2,
                                                      float* __restrict__ out) {
    __shared__ float sW1t[DD * WPAD];
    __shared__ float sW2[DD * DOUT];
    __shared__ float tbuf[4][DD];
    __shared__ float ubuf[4][DD];
    const int lane = threadIdx.x & 63;
    const int wv   = threadIdx.x >> 6;
    const int sub  = lane >> 4;   // also the K-quarter for the 2nd matmul
    const int m    = lane & 15;

    stage_wt(Wf1, sW1t, threadIdx.x);
    for (int i = threadIdx.x; i < DD * DOUT / 4; i += 256)
        ((float4*)sW2)[i] = ((const float4*)Wf2)[i];
    __syncthreads();

    const float4 b3v4 = ((const float4*)b3)[m];
    const float  b1v  = bf1[lane];
    const float  b2v  = bf2[m];
    const float4* hpv  = (const float4*)hp;
    const float4* w1col = (const float4*)(sW1t + lane * WPAD);
    const float*  w2p   = sW2 + (sub * 16) * DOUT + m;  // (sub*16+k')*16 + m

    int base = (blockIdx.x * 4 + wv) * NPW;
    for (int r = 0; r < NPW; ++r) {
        int n = base + r;
        if (n >= NN) return;
        int c = cnt[n]; if (c > 63) c = 63;
        float dv = rsqrtf((float)cnt[n] + 1.0f);
        float4 s = gather_node(hpv, csr + (size_t)n * CAP, n, c, sub, m);
        float4 t4;
        t4.x = fmaxf(fmaf(dv, s.x, b3v4.x), 0.f);
        t4.y = fmaxf(fmaf(dv, s.y, b3v4.y), 0.f);
        t4.z = fmaxf(fmaf(dv, s.z, b3v4.z), 0.f);
        t4.w = fmaxf(fmaf(dv, s.w, b3v4.w), 0.f);

        if (sub == 0) ((float4*)tbuf[wv])[m] = t4;
        const float4* tb = (const float4*)tbuf[wv];
        float u = b1v;
#pragma unroll
        for (int kk = 0; kk < DD / 4; ++kk) {
            float4 w = w1col[kk];
            float4 q = tb[kk];
            u = fmaf(q.x, w.x, fmaf(q.y, w.y, fmaf(q.z, w.z, fmaf(q.w, w.w, u))));
        }
        u = fmaxf(u, 0.f);

        // out = u @ Wf2 + bf2 : lane (sub,m) does quarter-K partial, 2 xor-reduces
        ubuf[wv][lane] = u;
        const float4* ub = (const float4*)(ubuf[wv] + sub * 16);
        float p = 0.f;
#pragma unroll
        for (int kq = 0; kq < 4; ++kq) {
            float4 z = ub[kq];
            p = fmaf(z.x, w2p[(4 * kq + 0) * DOUT],
                fmaf(z.y, w2p[(4 * kq + 1) * DOUT],
                fmaf(z.z, w2p[(4 * kq + 2) * DOUT],
                fmaf(z.w, w2p[(4 * kq + 3) * DOUT], p))));
        }
        p += __shfl_xor(p, 16);
        p += __shfl_xor(p, 32);
        if (lane < 16) out[(size_t)n * DOUT + m] = p + b2v;
    }
}

// ---------------------------------------------------------------------------
extern "C" void kernel_launch(void* const* d_in, const int* in_sizes, int n_in,
                              void* d_out, int out_size, void* d_ws, size_t ws_size,
                              hipStream_t stream) {
    const float* x   = (const float*)d_in[0];
    const int*   ei  = (const int*)d_in[1];
    const float* W1  = (const float*)d_in[2];
    const float* b1  = (const float*)d_in[3];
    const float* W2  = (const float*)d_in[4];
    const float* b2  = (const float*)d_in[5];
    const float* W3  = (const float*)d_in[6];
    const float* b3  = (const float*)d_in[7];
    const float* Wf1 = (const float*)d_in[8];
    const float* bf1 = (const float*)d_in[9];
    const float* Wf2 = (const float*)d_in[10];
    const float* bf2 = (const float*)d_in[11];
    float* out = (float*)d_out;

    char* ws = (char*)d_ws;
    auto al = [](size_t v) { return (v + 255) & ~(size_t)255; };
    size_t off = 0;
    int*   cnt  = (int*)(ws + off);   off = al(off + (size_t)NN * 4);
    int*   csr  = (int*)(ws + off);   off = al(off + (size_t)NN * CAP * 4);
    float* A    = (float*)(ws + off); off = al(off + (size_t)(NN + 1) * DD * 4);
    float* B    = (float*)(ws + off); off = al(off + (size_t)(NN + 1) * DD * 4);

    // Lifetime-disjoint aliases: binned int2 edges in A's first 12.8 MB
    // (consumed by k_csr, then overwritten by k_scale); hist matrix in B's
    // first 154 KB (consumed by k_csr, overwritten by k_fused_l1 output).
    int2* bed  = (int2*)A;
    int*  hist = (int*)B;

    k_hist<<<NBL, 256, 0, stream>>>(ei, hist, cnt);
    k_scan<<<1, 256, 0, stream>>>(hist, A, B);
    k_scatter<<<NBL, 256, 0, stream>>>(ei, hist, bed);
    k_csr<<<NB, 256, 0, stream>>>(bed, hist, cnt, csr);

    int gf = (NN + 4 * NPW - 1) / (4 * NPW);       // fused grid: 3125 blocks

    // xs = x * dinv  -> A   (replaces the 110us k_gemm_scale; see k_scale doc)
    k_scale<<<(NN * (DD / 4) + 255) / 256, 256, 0, stream>>>(x, cnt, A);
    // layer 1 (gather xs, @W1, relu, @W2) -> B = hp1
    k_fused_l1<<<gf, 256, 0, stream>>>(A, csr, cnt, b1, W1, W2, B);
    // layer 2->3: agg(hp1)+relu+b2, then hp2 = (t@W3)*dinv -> A
    k_fused<<<gf, 256, 0, stream>>>(B, csr, cnt, b2, W3, A);
    // layer 3 + FFN -> out
    k_fused_ffn<<<gf, 256, 0, stream>>>(A, csr, cnt, b3, Wf1, bf1, Wf2, bf2, out);
}